// Round 10
// baseline (697.139 us; speedup 1.0000x reference)
//
#include <hip/hip_runtime.h>

#define NB 64
#define NC 32
#define NH 16
#define NW 16
#define NE 4096
#define NTOT (NB*NC*NH*NW)   // 524288
#define IDXW 341             // 1+4+16+64+256
#define GRID 256
#define TPB 1024

typedef float f32x2 __attribute__((ext_vector_type(2)));
typedef float f32x4 __attribute__((ext_vector_type(4)));

__device__ __forceinline__ f32x2 pkfma(f32x2 a, f32x2 b, f32x2 c) {
#if __has_builtin(__builtin_elementwise_fma)
  return __builtin_elementwise_fma(a, b, c);
#else
  return (f32x2){fmaf(a.x, b.x, c.x), fmaf(a.y, b.y, c.y)};
#endif
}

__device__ __forceinline__ double cubicw(double x) {
  const double A = -0.75;
  x = fabs(x);
  if (x <= 1.0) return ((A + 2.0) * x - (A + 3.0)) * x * x + 1.0;
  if (x < 2.0)  return A * (((x - 5.0) * x + 8.0) * x - 4.0);
  return 0.0;
}

// monotonic u32 key: smaller float <=> smaller key (handles negatives)
__device__ __forceinline__ unsigned monokey(float f) {
  unsigned u = __float_as_uint(f);
  return (u & 0x80000000u) ? ~u : (u | 0x80000000u);
}

__device__ __forceinline__ unsigned aload(unsigned* p) {
  return __hip_atomic_load(p, __ATOMIC_RELAXED, __HIP_MEMORY_SCOPE_AGENT);
}
__device__ __forceinline__ double aloadd(double* p) {
  return __hip_atomic_load(p, __ATOMIC_RELAXED, __HIP_MEMORY_SCOPE_AGENT);
}

// 4-party group barrier, fence-free (proven R2-R9): sc0sc1 publishes are
// coherent at IF$; __syncthreads drains vmcnt before arrive.
__device__ __forceinline__ void groupbar(unsigned* fl) {
  __syncthreads();
  if (threadIdx.x == 0) {
    __hip_atomic_fetch_add(fl, 1u, __ATOMIC_RELAXED, __HIP_MEMORY_SCOPE_AGENT);
    while (aload(fl) < 4u) __builtin_amdgcn_s_sleep(1);
  }
  __syncthreads();
}

// R7-R9 lesson: compiler pins 64 VGPR and SPILLS anything bigger (R7/R8:
// 3.9GB scratch traffic). Scan keeps stream-loop liveness at R5's proven
// level: acc[8] f32x2 = 16 regs, nothing else live across the k2 loop.
// R9 lesson: "rows per stream" only matters per STREAMED BYTE -- this round
// splits CODES across the group (2048/block) so 8 rows share a 256KB stream:
// 32KB/row vs R5's 128KB/row -> per-block L2 stream 13.3 -> 5.75 MB.
__global__ __launch_bounds__(TPB)
__attribute__((amdgpu_waves_per_eu(4, 4)))
void k_fused(
    const float* __restrict__ z, const float* __restrict__ emb,
    const float* __restrict__ phi_w, const float* __restrict__ phi_b,
    double* __restrict__ rv64, double* __restrict__ emb_sq,
    double* __restrict__ loss_d, float* __restrict__ emb_ti,
    float* __restrict__ emb_sq32, unsigned* __restrict__ cand_ws,
    unsigned* __restrict__ cnt, unsigned* __restrict__ gbar,
    unsigned* __restrict__ flags,
    float* __restrict__ out_zhat, float* __restrict__ out_loss,
    float* __restrict__ out_idx)
{
  __shared__ double lds[8192];                 // 64 KB
  char* base = (char*)lds;
  double* zres = lds;                          // [8][256] f64, persistent [0,16K)
  char* qreg   = base + 16384;                 // 32 KB multi-use [16K,48K)
  char* ttreg  = base + 49152;                 // 16 KB multi-use [48K,64K)

  const int tid = threadIdx.x;
  // group = {b, b+64, b+128, b+192}: all == b (mod 8) -> same XCD under the
  // default bid%8 XCD round-robin -> exchange stays XCD-local.
  const int b = blockIdx.x & 63, jq = blockIdx.x >> 6;
  const int co0 = jq * 8;
  const int ch = jq & 1, rh = jq >> 1;         // code-half / row-half

  // idempotent CAS-init of poisoned (0xAA) sync cells (32 flags per group)
  if (tid < 32) atomicCAS(&flags[(b << 5) + tid], 0xAAAAAAAAu, 0u);
  if (tid == 0) {
    atomicCAS((unsigned long long*)loss_d, 0xAAAAAAAAAAAAAAAAull, 0ull);
    atomicCAS(cnt, 0xAAAAAAAAu, 0u);
    atomicCAS(gbar, 0xAAAAAAAAu, 0u);
  }

  // ---------- setup: zres <- z slice; emb_ti (k-pair interleave) + emb_sq ---
  #pragma unroll
  for (int t = 0; t < 2; t++) {
    int i = t * TPB + tid;
    zres[i] = (double)z[((b * NC + co0) << 8) + i];
  }
  {
    int c0 = blockIdx.x * 16;                  // 16 codes per block
    if (tid < 512) {
      int cl = tid >> 5, k = tid & 31;
      // layout: emb_ti[k2*8192 + code*2 + (k&1)]
      emb_ti[(k >> 1) * 8192 + (c0 + cl) * 2 + (k & 1)] = emb[(c0 + cl) * NC + k];
    }
    if (tid < 16) {
      const float* er = emb + (c0 + tid) * NC;
      double s = 0.0;
      #pragma unroll
      for (int j = 0; j < 8; j++)
        s += (double)er[4*j]*er[4*j] + (double)er[4*j+1]*er[4*j+1]
           + (double)er[4*j+2]*er[4*j+2] + (double)er[4*j+3]*er[4*j+3];
      emb_sq[c0 + tid] = s;
      emb_sq32[c0 + tid] = (float)s;
    }
  }
  // one-time FENCED tree barrier (only threadfence pair in the kernel):
  // publishes emb_ti/emb_sq/emb_sq32 for normal L2-cached reads thereafter.
  __syncthreads();
  if (tid == 0) {
    __threadfence();                           // release (wb L2)
    __hip_atomic_fetch_add(&flags[(b << 5) + 31], 1u, __ATOMIC_RELAXED,
                           __HIP_MEMORY_SCOPE_AGENT);
    if (jq == 0) {
      while (aload(&flags[(b << 5) + 31]) < 4u) __builtin_amdgcn_s_sleep(1);
      __hip_atomic_fetch_add(gbar, 1u, __ATOMIC_RELAXED,
                             __HIP_MEMORY_SCOPE_AGENT);
      while (aload(gbar) < 64u) __builtin_amdgcn_s_sleep(4);
      __hip_atomic_store(&flags[(b << 5) + 30], 1u, __ATOMIC_RELAXED,
                         __HIP_MEMORY_SCOPE_AGENT);
    } else {
      while (aload(&flags[(b << 5) + 30]) < 1u) __builtin_amdgcn_s_sleep(1);
    }
    __threadfence();                           // acquire (inv L2)
  }
  __syncthreads();

  double bloss = 0.0;
  // ticks = np.linspace(1/12, 11/12, 4) f64: si=2 tie breaks to pi=2
  const int pis[5]  = {0, 1, 2, 2, 3};
  const int offs[5] = {0, 1, 5, 21, 85};

  for (int si = 0; si < 5; si++) {
    const int ph = 1 << si, f = NH / ph, ph2 = ph * ph;
    const int idx_off = offs[si];

    // ---------- pool own 8 channels (f64) -> publish rv64 [b][n][c] ---------
    if (si == 4) {
      #pragma unroll
      for (int t = 0; t < 2; t++) {
        int i = t * TPB + tid;
        int pix = i >> 3, cc = i & 7;          // coalesced publish
        __hip_atomic_store(&rv64[(((b << 8) + pix) << 5) + co0 + cc],
                           zres[cc * 256 + pix],
                           __ATOMIC_RELAXED, __HIP_MEMORY_SCOPE_AGENT);
      }
    } else {
      double* pp = (double*)qreg;              // partials  [16K,24K)
      double* pooled = (double*)(qreg + 8192); // [8][ph2]  [24K,28K)
      const int P = (f >= 8) ? 8 : f;          // si0:8 si1:8 si2:4 si3:2
      const int lP = (f >= 8) ? 3 : ((f == 4) ? 2 : 1);
      const int items = 8 * ph2, work = items * P, dpp = f / P;
      if (tid < work) {
        int it = tid >> lP, part = tid & (P - 1);
        int cc = it >> (2 * si), rem = it & (ph2 - 1);
        int y = rem >> si, x = rem & (ph - 1);
        const double* basep = zres + cc * 256 + (y * f) * 16 + x * f;
        double s = 0.0;
        for (int dy = part * dpp; dy < part * dpp + dpp; dy++) {
          const double* rp = basep + dy * 16;
          #pragma unroll 4
          for (int dx = 0; dx < f; dx++) s += rp[dx];
        }
        pp[tid] = s;
      }
      __syncthreads();
      if (tid < items) {
        double s = 0.0;
        for (int p2 = 0; p2 < P; p2++) s += pp[(tid << lP) + p2];
        pooled[tid] = s / (double)(f * f);     // tid = cc*ph2+rem
      }
      __syncthreads();
      if (tid < items) {
        int rem = tid >> 3, cc = tid & 7;      // coalesced publish
        __hip_atomic_store(&rv64[(((b << 8) + rem) << 5) + co0 + cc],
                           pooled[cc * ph2 + rem],
                           __ATOMIC_RELAXED, __HIP_MEMORY_SCOPE_AGENT);
      }
    }
    groupbar(&flags[(b << 5) + si * 3]);       // barA: rv64 ready

    // ---------- scan: code-half ch (2048 codes), row-half rh ----------------
    {
      const int half = (ph2 + 1) >> 1;
      int rows_start = rh * half; if (rows_start > ph2) rows_start = ph2;
      int rows_end = rows_start + half; if (rows_end > ph2) rows_end = ph2;
      const int nrows = rows_end - rows_start;     // si0: 1/0; si4: 128
      float* rvt32 = (float*)(base + 16384);       // [<=128][32] f32 16KB
      unsigned long long* wdu = (unsigned long long*)(base + 32768); // 2KB
      const int nstage = (nrows + 7) & ~7;
      for (int t = tid; t < nstage * 32; t += TPB) {
        int m = t >> 5, k = t & 31;
        int n = rows_start + m; if (n > ph2 - 1) n = ph2 - 1;  // pad=last row
        rvt32[t] = (float)aloadd(&rv64[(((b << 8) + n) << 5) + k]);
      }
      __syncthreads();
      if (nrows) {
        const int e0 = ch * 2048 + (tid << 1);     // 2 consecutive codes
        const f32x2 es = *(const f32x2*)(emb_sq32 + e0);
        const int lane = tid & 63, wv_ = tid >> 6;
        const f32x4* __restrict__ ebase =
            (const f32x4*)emb_ti + (ch ? 1024 : 0) + tid;
        for (int m0 = 0; m0 < nrows; m0 += 8) {
          f32x2 acc[8];                            // 16 VGPR (R5-proven level)
          #pragma unroll
          for (int j = 0; j < 8; j++) acc[j] = (f32x2){0.f, 0.f};
          #pragma unroll 4
          for (int k2 = 0; k2 < 16; k2++) {
            f32x4 E = ebase[k2 * 2048];            // codes e0,e0+1 (k pair)
            #pragma unroll
            for (int j = 0; j < 8; j++) {
              f32x2 r2 = *(const f32x2*)(rvt32 + ((m0 + j) << 5) + (k2 << 1));
              acc[j] = pkfma((f32x2){r2.x, r2.x}, (f32x2){E.x, E.z}, acc[j]);
              acc[j] = pkfma((f32x2){r2.y, r2.y}, (f32x2){E.y, E.w}, acc[j]);
            }
          }
          #pragma unroll
          for (int j = 0; j < 8; j++) {            // exact per-half top-2
            float d0 = es.x - 2.f * acc[j].x;
            float d1 = es.y - 2.f * acc[j].y;
            unsigned long long k0 =
                ((unsigned long long)monokey(d0) << 32) | (unsigned)e0;
            unsigned long long k1 =
                ((unsigned long long)monokey(d1) << 32) | (unsigned)(e0 + 1);
            unsigned long long p1 = k0 < k1 ? k0 : k1;
            unsigned long long p2 = k0 < k1 ? k1 : k0;
            #pragma unroll
            for (int off = 32; off >= 1; off >>= 1) {  // wave top-2 butterfly
              unsigned long long q1 = __shfl_xor(p1, off, 64);
              unsigned long long q2 = __shfl_xor(p2, off, 64);
              unsigned long long lo = p1 < q1 ? p1 : q1;
              unsigned long long hi = p1 < q1 ? q1 : p1;
              unsigned long long m2 = p2 < q2 ? p2 : q2;
              p1 = lo;
              p2 = hi < m2 ? hi : m2;
            }
            if (lane == 0) {
              wdu[(wv_ << 4) + (j << 1)]     = p1;
              wdu[(wv_ << 4) + (j << 1) + 1] = p2;
            }
          }
          __syncthreads();
          if (tid < 8 && m0 + tid < nrows) {       // cross-wave top-2 merge
            unsigned long long G1 = ~0ull, G2 = ~0ull;
            #pragma unroll
            for (int w = 0; w < 16; w++) {
              unsigned long long a1 = wdu[(w << 4) + (tid << 1)];
              unsigned long long a2 = wdu[(w << 4) + (tid << 1) + 1];
              if (a1 < G1) { G2 = (G1 < a2 ? G1 : a2); G1 = a1; }
              else if (a1 < G2) G2 = a1;
            }
            int n = rows_start + m0 + tid;
            unsigned* cw = cand_ws + (((((b << 1) + ch) << 8) + n) << 1);
            __hip_atomic_store(&cw[0], (unsigned)(G1 & 0xFFFFu),
                               __ATOMIC_RELAXED, __HIP_MEMORY_SCOPE_AGENT);
            __hip_atomic_store(&cw[1], (unsigned)(G2 & 0xFFFFu),
                               __ATOMIC_RELAXED, __HIP_MEMORY_SCOPE_AGENT);
          }
          __syncthreads();                         // wdu reused next chunk
        }
      }
    }
    groupbar(&flags[(b << 5) + si * 3 + 1]);   // barB: cands ready

    // ---------- rescore (redundant per block): 4 cands/row, f64, winner ----
    // union of per-half f32-top-2 contains the global f32-top-2, so the f64
    // winner is at least as exact as the proven global-top-2 rescore.
    {
      unsigned short* fidx = (unsigned short*)(ttreg + 12800);   // [256]
      if (tid < 4 * ph2) {
        int n = tid >> 2, cs = tid & 3;
        int c = (int)aload(&cand_ws[(((((b << 1) + (cs >> 1)) << 8) + n) << 1)
                                    + (cs & 1)]);
        const float* er = emb + (c << 5);
        double* rrow = rv64 + (((b << 8) + n) << 5);
        double dot = 0.0;
        #pragma unroll
        for (int k = 0; k < 32; k++)
          dot = fma(aloadd(&rrow[k]), (double)er[k], dot);
        double d = emb_sq[c] - 2.0 * dot;
        #pragma unroll
        for (int off = 1; off <= 2; off <<= 1) {   // 4-lane min, tie->low idx
          double od = __shfl_xor(d, off, 64);
          int oc = __shfl_xor(c, off, 64);
          if (od < d || (od == d && oc < c)) { d = od; c = oc; }
        }
        if (cs == 0) {
          fidx[n] = (unsigned short)c;
          if (jq == 0) out_idx[b * IDXW + idx_off + n] = (float)c;
        }
      }
    }
    groupbar(&flags[(b << 5) + si * 3 + 2]);   // barC: rv64 reads done before
                                               // any block's next pool writes
    unsigned short* fidx = (unsigned short*)(ttreg + 12800);

    // ---------- upsample (f32): full 32-ch q in LDS (redundant x4) ----------
    float* simg = (float*)qreg;                // [32][256] f32, 32KB
    if (si == 4) {
      for (int i = tid; i < 32 * 256; i += TPB)
        simg[i] = emb[(int)fidx[i & 255] * NC + (i >> 8)];
    } else {
      float* wtab = (float*)(ttreg + 12288);   // [16][4] f32
      int* itab = (int*)(ttreg + 12544);       // [16]
      double scale = (double)ph / 16.0;
      if (tid < 64) {
        int oy = tid >> 2, kk = tid & 3;
        double src = ((double)oy + 0.5) * scale - 0.5;
        double fi = floor(src);
        if (kk == 0) itab[oy] = (int)fi;
        wtab[tid] = (float)cubicw(src - fi - (double)(kk - 1));
      }
      __syncthreads();
      int CH = (si == 3) ? 16 : 32, nhalf = (si == 3) ? 2 : 1;
      float* qs = (float*)(ttreg + 8192);      // <=4KB gather buf
      float* tt = (float*)ttreg;               // <=8KB H-pass intermediate
      for (int hlf = 0; hlf < nhalf; hlf++) {
        int c0 = hlf * CH;
        for (int i = tid; i < CH * ph2; i += TPB) {
          int cc = i >> (2 * si), rem = i & (ph2 - 1);
          qs[i] = emb[(int)fidx[rem] * NC + c0 + cc];
        }
        __syncthreads();
        for (int i = tid; i < CH * 16 * ph; i += TPB) {   // H pass (y)
          int x = i & (ph - 1), oy = (i >> si) & 15, cc = i >> (4 + si);
          int i0 = itab[oy];
          float s = 0.f;
          #pragma unroll
          for (int k = 0; k < 4; k++) {
            int iy = min(max(i0 + k - 1, 0), ph - 1);
            s = fmaf(wtab[oy * 4 + k], qs[(cc * ph + iy) * ph + x], s);
          }
          tt[i] = s;
        }
        __syncthreads();
        for (int i = tid; i < CH * 256; i += TPB) {       // W pass (x)
          int ox = i & 15, oy = (i >> 4) & 15, cc = i >> 8;
          int i0 = itab[ox];
          float s = 0.f;
          #pragma unroll
          for (int k = 0; k < 4; k++) {
            int ix = min(max(i0 + k - 1, 0), ph - 1);
            s = fmaf(wtab[ox * 4 + k], tt[(cc * 16 + oy) * ph + ix], s);
          }
          simg[(c0 + cc) * 256 + oy * 16 + ox] = s;
        }
        __syncthreads();
      }
    }
    __syncthreads();

    // ---------- phi (packed f32): 0.5*x + 0.5*(conv3x3(x)+b); zres f64 ------
    {
      float* lw2 = (float*)ttreg;              // co-pair interleaved, 9216B
      const float* wsrc = phi_w + (pis[si] * NC + co0) * NC * 9;
      for (int i = tid; i < 2304; i += TPB) {
        int co = i / 288, rem = i - co * 288;  // rem = ci*9+k
        lw2[(((co >> 1) * 288 + rem) << 1) + (co & 1)] = wsrc[i];
      }
      __syncthreads();
      int pix = tid & 255, sub = tid >> 8;     // 4 subs x 2 co = 8 co
      int x = pix & 15, y = pix >> 4;
      f32x2 a = {0.f, 0.f};
      const f32x2* wp = (const f32x2*)lw2 + sub * 288;
      for (int ci = 0; ci < NC; ci++) {
        float wv[9];
        #pragma unroll
        for (int ky = 0; ky < 3; ky++) {
          int yy = y + ky - 1;
          #pragma unroll
          for (int kx = 0; kx < 3; kx++) {
            int xx = x + kx - 1;
            wv[ky * 3 + kx] = (yy >= 0 && yy < NH && xx >= 0 && xx < NW)
                              ? simg[(ci << 8) + yy * 16 + xx] : 0.f;
          }
        }
        #pragma unroll
        for (int k = 0; k < 9; k++)
          a = pkfma((f32x2){wv[k], wv[k]}, wp[ci * 9 + k], a);
      }
      double lsum = 0.0;
      #pragma unroll
      for (int jj = 0; jj < 2; jj++) {
        int col = (sub << 1) + jj;
        float aj = jj ? a.y : a.x;
        float val = simg[((co0 + col) << 8) + pix] * 0.5f
                  + (aj + phi_b[pis[si] * NC + co0 + col]) * 0.5f;
        int li = (col << 8) + pix;
        double zr = zres[li] - (double)val;
        zres[li] = zr;
        if (si == 4) {
          int gi = ((b * NC + co0 + col) << 8) + pix;
          out_zhat[gi] = (float)((double)z[gi] - zr);
        }
        lsum += zr * zr;                       // z_hat - z == -z_res
      }
      __syncthreads();                         // simg consumed
      // shuffle-based loss reduction
      #pragma unroll
      for (int off = 32; off >= 1; off >>= 1)
        lsum += __shfl_xor(lsum, off, 64);
      double* red = (double*)qreg;
      if ((tid & 63) == 0) red[tid >> 6] = lsum;
      __syncthreads();
      if (tid < 16) {
        double v = red[tid];
        #pragma unroll
        for (int off = 8; off >= 1; off >>= 1) v += __shfl_xor(v, off, 16);
        if (tid == 0) bloss += v;
      }
      __syncthreads();
    }
  }

  // ---------- global loss: one f64 atomic per block; last arriver writes ----
  if (tid == 0) {
    double old = unsafeAtomicAdd(loss_d, bloss); (void)old;
    asm volatile("s_waitcnt vmcnt(0)" ::: "memory");
    unsigned n = __hip_atomic_fetch_add(cnt, 1u, __ATOMIC_RELAXED,
                                        __HIP_MEMORY_SCOPE_AGENT);
    if (n == GRID - 1u) {
      double tot = __hip_atomic_load(loss_d, __ATOMIC_RELAXED,
                                     __HIP_MEMORY_SCOPE_AGENT);
      *out_loss = (float)(tot * (1.25 / (5.0 * (double)NTOT)));
    }
  }
}

extern "C" void kernel_launch(void* const* d_in, const int* in_sizes, int n_in,
                              void* d_out, int out_size, void* d_ws, size_t ws_size,
                              hipStream_t stream) {
  const float* z     = (const float*)d_in[0];   // [64,32,16,16]
  const float* emb   = (const float*)d_in[1];   // [4096,32]
  const float* phi_w = (const float*)d_in[2];   // [4,32,32,3,3]
  const float* phi_b = (const float*)d_in[3];   // [4,32]

  float* out      = (float*)d_out;
  float* out_zhat = out;
  float* out_loss = out + NTOT;
  float* out_idx  = out + NTOT + 1;             // [64,341] as floats

  double* ws        = (double*)d_ws;
  double* rv64      = ws;                            // 64*256*32 f64 = 4 MB
  double* emb_sq    = rv64 + 64 * 256 * NC;          // 4096 f64
  double* loss_d    = emb_sq + NE;                   // 1 f64 (+1 pad for 16B)
  float*  emb_ti    = (float*)(loss_d + 2);          // 131072 f32 (16B aligned)
  float*  emb_sq32  = emb_ti + NE * NC;              // 4096 f32
  unsigned* cand_ws = (unsigned*)(emb_sq32 + NE);    // 64*2*256*2 u32 = 256KB
  unsigned* cnt     = cand_ws + 64 * 2 * 256 * 2;    // 1
  unsigned* gbar    = cnt + 1;                       // 1
  unsigned* flags   = gbar + 1;                      // 64*32 one-shot cells

  k_fused<<<GRID, TPB, 0, stream>>>(z, emb, phi_w, phi_b,
                                    rv64, emb_sq, loss_d, emb_ti, emb_sq32,
                                    cand_ws, cnt, gbar, flags,
                                    out_zhat, out_loss, out_idx);
}